// Round 2
// baseline (206.096 us; speedup 1.0000x reference)
//
#include <hip/hip_runtime.h>
#include <hip/hip_bf16.h>

#define N_SAMPLES 128
#define LAST_DIST 1e10f
#define EPS 1e-10f

__device__ __forceinline__ float sigmoidf(float x) {
    return 1.0f / (1.0f + expf(-x));
}

// One 64-lane wave per ray. Lane l owns samples (l, 64+l) so that every
// global load is unit-stride across the wave (perfect coalescing).
__global__ __launch_bounds__(256) void render_rays_kernel(
    const float4* __restrict__ raw,   // [R * S] float4 (rgb + sigma)
    const float*  __restrict__ zv,    // [R * S] z_vals
    float* __restrict__ out,          // [R * 3]
    int n_rays)
{
    const int wave_in_block = threadIdx.x >> 6;
    const int lane = threadIdx.x & 63;
    const int r = blockIdx.x * (blockDim.x >> 6) + wave_in_block;
    if (r >= n_rays) return;

    const size_t base = (size_t)r * N_SAMPLES;

    // ---- loads: all unit-stride across the wave ----
    const float4 fa = raw[base + lane];        // sample l
    const float4 fb = raw[base + 64 + lane];   // sample 64+l
    const float  za = zv[base + lane];
    const float  zb = zv[base + 64 + lane];

    // ---- dists: d[i] = z[i+1] - z[i], last = 1e10 ----
    const float za_next = __shfl_down(za, 1);   // z[l+1]   (lane<63)
    const float zb_next = __shfl_down(zb, 1);   // z[65+l]  (lane<63)
    const float z64     = __shfl(zb, 0);        // z[64]
    const float da = ((lane == 63) ? z64 : za_next) - za;
    const float db = (lane == 63) ? LAST_DIST : (zb_next - zb);

    // ---- survival t = 1 - alpha + eps = exp(-relu(sigma)*d) + eps ----
    const float ea = expf(-fmaxf(fa.w, 0.0f) * da);
    const float eb = expf(-fmaxf(fb.w, 0.0f) * db);
    const float ta = ea + EPS;
    const float tb = eb + EPS;

    // ---- exclusive prefix product over 128 samples: two half-scans ----
    // first half (samples 0..63)
    float Pa = ta;
    #pragma unroll
    for (int off = 1; off < 64; off <<= 1) {
        const float v = __shfl_up(Pa, off);
        if (lane >= off) Pa *= v;
    }
    float Ta = __shfl_up(Pa, 1);                // exclusive
    if (lane == 0) Ta = 1.0f;
    const float total_a = __shfl(Pa, 63);       // prod of all first-half t

    // second half (samples 64..127)
    float Pb = tb;
    #pragma unroll
    for (int off = 1; off < 64; off <<= 1) {
        const float v = __shfl_up(Pb, off);
        if (lane >= off) Pb *= v;
    }
    float Tb = __shfl_up(Pb, 1);
    if (lane == 0) Tb = 1.0f;
    Tb *= total_a;

    // ---- weights & color accumulation ----
    const float wa = (1.0f - ea) * Ta;
    const float wb = (1.0f - eb) * Tb;

    float accx = wa * sigmoidf(fa.x) + wb * sigmoidf(fb.x);
    float accy = wa * sigmoidf(fa.y) + wb * sigmoidf(fb.y);
    float accz = wa * sigmoidf(fa.z) + wb * sigmoidf(fb.z);

    // ---- wave reduction (butterfly) ----
    #pragma unroll
    for (int off = 32; off > 0; off >>= 1) {
        accx += __shfl_xor(accx, off);
        accy += __shfl_xor(accy, off);
        accz += __shfl_xor(accz, off);
    }

    if (lane < 3) {
        out[(size_t)r * 3 + lane] = (lane == 0) ? accx : ((lane == 1) ? accy : accz);
    }
}

extern "C" void kernel_launch(void* const* d_in, const int* in_sizes, int n_in,
                              void* d_out, int out_size, void* d_ws, size_t ws_size,
                              hipStream_t stream) {
    const float4* raw = (const float4*)d_in[0];       // [R, S, 4] f32
    const float*  zv  = (const float*)d_in[1];        // [R, S]   f32
    float* out        = (float*)d_out;                // [R, 3]   f32

    const int n_rays = in_sizes[0] / (N_SAMPLES * 4);

    const int waves_per_block = 4;                    // 256 threads
    const int block = waves_per_block * 64;
    const int grid = (n_rays + waves_per_block - 1) / waves_per_block;

    render_rays_kernel<<<grid, block, 0, stream>>>(raw, zv, out, n_rays);
}